// Round 5
// baseline (2293.192 us; speedup 1.0000x reference)
//
#include <hip/hip_runtime.h>

typedef __bf16 bf16_t;
using bf16x8 = __bf16 __attribute__((ext_vector_type(8)));
using f32x4  = float __attribute__((ext_vector_type(4)));

// B=2048, N=64, D=256, H=256, T=16
static constexpr long MTOT = 131072;   // B*N

__device__ __forceinline__ f32x4 mfma16(bf16x8 a, bf16x8 b, f32x4 c) {
  return __builtin_amdgcn_mfma_f32_16x16x32_bf16(a, b, c, 0, 0, 0);
}

// Swizzled LDS tiles: element (row,k) at byte row*rowBytes + ((k*2 + colOff) ^ ((row&7)<<4)).
__device__ __forceinline__ bf16x8 lds_frag(const bf16_t* base, int row, int k, int rowBytes) {
  int byte = row * rowBytes + ((k << 1) ^ ((row & 7) << 4));
  return *reinterpret_cast<const bf16x8*>(reinterpret_cast<const char*>(base) + byte);
}
__device__ __forceinline__ void lds_put(bf16_t* base, int row, int col, int rowBytes, float v) {
  int byte = row * rowBytes + ((col << 1) ^ ((row & 7) << 4));
  *reinterpret_cast<bf16_t*>(reinterpret_cast<char*>(base) + byte) = (bf16_t)v;
}
__device__ __forceinline__ void lds_put2(bf16_t* hi, bf16_t* lo, int row, int col,
                                         int rowBytes, float v) {
  int byte = row * rowBytes + ((col << 1) ^ ((row & 7) << 4));
  bf16_t h = (bf16_t)v;
  bf16_t l = (bf16_t)(v - (float)h);
  *reinterpret_cast<bf16_t*>(reinterpret_cast<char*>(hi) + byte) = h;
  *reinterpret_cast<bf16_t*>(reinterpret_cast<char*>(lo) + byte) = l;
}

// Stage a [64 x 256] f32 tile (lda=256) -> split hi/lo bf16 swizzled LDS tiles.
__device__ __forceinline__ void stage_split(bf16_t* hi, bf16_t* lo, const float* src,
                                            long row0, int rowBytesLds, int colOffBytes,
                                            int tid, int nthr) {
  for (int e = tid * 4; e < 64 * 256; e += nthr * 4) {
    int r = e >> 8, c = e & 255;
    float4 v = *reinterpret_cast<const float4*>(src + (row0 + r) * 256 + c);
    bf16_t h4[4], l4[4];
    h4[0] = (bf16_t)v.x; l4[0] = (bf16_t)(v.x - (float)h4[0]);
    h4[1] = (bf16_t)v.y; l4[1] = (bf16_t)(v.y - (float)h4[1]);
    h4[2] = (bf16_t)v.z; l4[2] = (bf16_t)(v.z - (float)h4[2]);
    h4[3] = (bf16_t)v.w; l4[3] = (bf16_t)(v.w - (float)h4[3]);
    int db = r * rowBytesLds + (((c << 1) + colOffBytes) ^ ((r & 7) << 4));
    *reinterpret_cast<uint2*>(reinterpret_cast<char*>(hi) + db) = *reinterpret_cast<const uint2*>(h4);
    *reinterpret_cast<uint2*>(reinterpret_cast<char*>(lo) + db) = *reinterpret_cast<const uint2*>(l4);
  }
}

// ---------------------------------------------------------------------------
// Weights f32 -> bf16 in ws. Offsets (elements): fc_gru_w 0, in_proj_w 65536,
// out_proj_w 262144, att_w 327680, gru_wih 458752, gru_whh 655360, fc2_w 851968.
// ---------------------------------------------------------------------------
__global__ __launch_bounds__(256) void cvt_weights(const float* __restrict__ w0,
                                                   const float* __restrict__ w1,
                                                   const float* __restrict__ w2,
                                                   const float* __restrict__ w3,
                                                   const float* __restrict__ w4,
                                                   const float* __restrict__ w5,
                                                   const float* __restrict__ w6,
                                                   bf16_t* __restrict__ dst) {
  long e = ((long)blockIdx.x * 256 + threadIdx.x) * 4;
  const float* src; long off;
  if (e < 65536)       { src = w0; off = 0; }
  else if (e < 262144) { src = w1; off = 65536; }
  else if (e < 327680) { src = w2; off = 262144; }
  else if (e < 458752) { src = w3; off = 327680; }
  else if (e < 655360) { src = w4; off = 458752; }
  else if (e < 851968) { src = w5; off = 655360; }
  else                 { src = w6; off = 851968; }
  float4 v = *reinterpret_cast<const float4*>(src + (e - off));
  bf16_t o[4] = {(bf16_t)v.x, (bf16_t)v.y, (bf16_t)v.z, (bf16_t)v.w};
  *reinterpret_cast<uint2*>(dst + e) = *reinterpret_cast<const uint2*>(o);
}

// ---------------------------------------------------------------------------
// x = relu(inputs @ fc_gru_w^T + b): f32 in (split), f32 out. Tile 64x256.
// ---------------------------------------------------------------------------
__global__ __launch_bounds__(256) void gemm1(const float* __restrict__ X,
                                             const bf16_t* __restrict__ W,
                                             const float* __restrict__ Bi,
                                             float* __restrict__ C) {
  __shared__ bf16_t Ihi[64 * 256], Ilo[64 * 256];
  const int tid = threadIdx.x, lane = tid & 63, wv = tid >> 6;
  const int rl = lane & 15, kof = (lane >> 4) << 3, ro4 = (lane >> 4) << 2;
  const long m0 = (long)blockIdx.x * 64;
  stage_split(Ihi, Ilo, X, m0, 512, 0, tid, 256);
  __syncthreads();
  f32x4 acc[4][4] = {};
  for (int kk = 0; kk < 256; kk += 32) {
    bf16x8 ah[4], al[4], bb[4];
#pragma unroll
    for (int rt = 0; rt < 4; ++rt) {
      ah[rt] = lds_frag(Ihi, rt * 16 + rl, kk + kof, 512);
      al[rt] = lds_frag(Ilo, rt * 16 + rl, kk + kof, 512);
    }
#pragma unroll
    for (int ct = 0; ct < 4; ++ct)
      bb[ct] = *reinterpret_cast<const bf16x8*>(W + (long)(wv * 64 + ct * 16 + rl) * 256 + kk + kof);
#pragma unroll
    for (int rt = 0; rt < 4; ++rt)
#pragma unroll
      for (int ct = 0; ct < 4; ++ct) {
        acc[rt][ct] = mfma16(ah[rt], bb[ct], acc[rt][ct]);
        acc[rt][ct] = mfma16(al[rt], bb[ct], acc[rt][ct]);
      }
  }
#pragma unroll
  for (int ct = 0; ct < 4; ++ct) {
    int c = wv * 64 + ct * 16 + rl;
    float bv = Bi[c];
#pragma unroll
    for (int rt = 0; rt < 4; ++rt)
#pragma unroll
      for (int i = 0; i < 4; ++i)
        C[(m0 + rt * 16 + ro4 + i) * 256 + c] = fmaxf(acc[rt][ct][i] + bv, 0.f);
  }
}

// ---------------------------------------------------------------------------
// Fused per-sample attention, split-precision. Block = 1 sample, 512 thr/8 waves.
// Reads x (f32 [M,256]), writes x_att (f32 [M,256]). Mask is INT32 (bool->int).
// LDS union (144 KB): [0,64K) XHI|XLO (later CTXHI|CTXLO); [64K,96K) Q (later V^T);
// [96K,128K) K (later PHI|PLO); [128K,144K) SS f32[64][64].
// ---------------------------------------------------------------------------
__global__ __launch_bounds__(512) void attn_kernel(const float* __restrict__ Xf,
                                                   float* __restrict__ Xatt,
                                                   const bf16_t* __restrict__ Wqkv,
                                                   const float* __restrict__ Bqkv,
                                                   const bf16_t* __restrict__ Wo,
                                                   const float* __restrict__ Bo,
                                                   const int* __restrict__ drop) {
  __shared__ __align__(16) char buf[147456];
  bf16_t* XHI = reinterpret_cast<bf16_t*>(buf);            // 32K, swz rowBytes 512
  bf16_t* XLO = reinterpret_cast<bf16_t*>(buf + 32768);    // 32K
  bf16_t* QS  = reinterpret_cast<bf16_t*>(buf + 65536);    // 32K, swz 512; later V^T swz 128
  bf16_t* KS  = reinterpret_cast<bf16_t*>(buf + 98304);    // 32K, swz 512; later PHI/PLO swz 128
  bf16_t* PHI = KS;                                        // 8K  [64][64]
  bf16_t* PLO = reinterpret_cast<bf16_t*>(buf + 98304 + 8192);
  float*  SS  = reinterpret_cast<float*>(buf + 131072);    // 16K [64][64]
  const int tid = threadIdx.x, lane = tid & 63, wv = tid >> 6;
  const int rl = lane & 15, kof = (lane >> 4) << 3, ro4 = (lane >> 4) << 2;
  const int b = blockIdx.x;
  const long R0 = (long)b * 64;
  stage_split(XHI, XLO, Xf, R0, 512, 0, tid, 512);
  __syncthreads();
  const int c0 = wv * 32;

  // q and k GEMMs (split x) -> bf16 swizzled LDS
  for (int which = 0; which < 2; ++which) {
    const bf16_t* Wp = Wqkv + (long)which * 65536;
    bf16_t* outp = which ? KS : QS;
    f32x4 acc[4][2] = {};
    for (int kk = 0; kk < 256; kk += 32) {
      bf16x8 ah[4], al[4], bb[2];
#pragma unroll
      for (int rt = 0; rt < 4; ++rt) {
        ah[rt] = lds_frag(XHI, rt * 16 + rl, kk + kof, 512);
        al[rt] = lds_frag(XLO, rt * 16 + rl, kk + kof, 512);
      }
#pragma unroll
      for (int ct = 0; ct < 2; ++ct)
        bb[ct] = *reinterpret_cast<const bf16x8*>(Wp + (long)(c0 + ct * 16 + rl) * 256 + kk + kof);
#pragma unroll
      for (int rt = 0; rt < 4; ++rt)
#pragma unroll
        for (int ct = 0; ct < 2; ++ct) {
          acc[rt][ct] = mfma16(ah[rt], bb[ct], acc[rt][ct]);
          acc[rt][ct] = mfma16(al[rt], bb[ct], acc[rt][ct]);
        }
    }
#pragma unroll
    for (int ct = 0; ct < 2; ++ct) {
      int c = c0 + ct * 16 + rl;
      float bv = Bqkv[which * 256 + c];
#pragma unroll
      for (int rt = 0; rt < 4; ++rt)
#pragma unroll
        for (int i = 0; i < 4; ++i) lds_put(outp, rt * 16 + ro4 + i, c, 512, acc[rt][ct][i] + bv);
    }
  }
  __syncthreads();

  // scores = q k^T * scale, masked (int32 mask) -> SS f32
  {
    const int rt0 = (wv & 3) * 16, sc0 = (wv >> 2) * 32;
    f32x4 acc[2] = {};
    for (int kk = 0; kk < 256; kk += 32) {
      bf16x8 a = lds_frag(QS, rt0 + rl, kk + kof, 512);
#pragma unroll
      for (int ct = 0; ct < 2; ++ct) {
        bf16x8 bb = lds_frag(KS, sc0 + ct * 16 + rl, kk + kof, 512);
        acc[ct] = mfma16(a, bb, acc[ct]);
      }
    }
#pragma unroll
    for (int ct = 0; ct < 2; ++ct)
#pragma unroll
      for (int i = 0; i < 4; ++i) {
        int rr = rt0 + ro4 + i, cc = sc0 + ct * 16 + rl;
        float s = acc[ct][i] * 0.0625f;
        if (drop[(long)b * 4096 + rr * 64 + cc]) s = -1e9f;
        SS[rr * 64 + cc] = s;
      }
  }
  __syncthreads();

  // v GEMM (split x) -> V^T [256][64] bf16 over Q region (q dead)
  {
    const bf16_t* Wp = Wqkv + (long)2 * 65536;
    f32x4 acc[4][2] = {};
    for (int kk = 0; kk < 256; kk += 32) {
      bf16x8 ah[4], al[4], bb[2];
#pragma unroll
      for (int rt = 0; rt < 4; ++rt) {
        ah[rt] = lds_frag(XHI, rt * 16 + rl, kk + kof, 512);
        al[rt] = lds_frag(XLO, rt * 16 + rl, kk + kof, 512);
      }
#pragma unroll
      for (int ct = 0; ct < 2; ++ct)
        bb[ct] = *reinterpret_cast<const bf16x8*>(Wp + (long)(c0 + ct * 16 + rl) * 256 + kk + kof);
#pragma unroll
      for (int rt = 0; rt < 4; ++rt)
#pragma unroll
        for (int ct = 0; ct < 2; ++ct) {
          acc[rt][ct] = mfma16(ah[rt], bb[ct], acc[rt][ct]);
          acc[rt][ct] = mfma16(al[rt], bb[ct], acc[rt][ct]);
        }
    }
#pragma unroll
    for (int ct = 0; ct < 2; ++ct) {
      int c = c0 + ct * 16 + rl;
      float bv = Bqkv[512 + c];
#pragma unroll
      for (int rt = 0; rt < 4; ++rt)
#pragma unroll
        for (int i = 0; i < 4; ++i) {
          int j = rt * 16 + ro4 + i;                    // agent (key) index
          lds_put(QS, c, j, 128, acc[rt][ct][i] + bv);  // V^T[c][j]
        }
    }
  }
  // wave-parallel softmax -> split P over K region (k dead)
  for (int j = 0; j < 8; ++j) {
    int rr = wv * 8 + j;
    float s = SS[rr * 64 + lane];
    float m = s;
#pragma unroll
    for (int off = 32; off >= 1; off >>= 1) m = fmaxf(m, __shfl_xor(m, off));
    float e = __expf(s - m);
    float sum = e;
#pragma unroll
    for (int off = 32; off >= 1; off >>= 1) sum += __shfl_xor(sum, off);
    lds_put2(PHI, PLO, rr, lane, 128, e / sum);
  }
  __syncthreads();

  // ctx = P @ V (split P) -> split ctx over X region (x dead)
  {
    f32x4 acc[4][2] = {};
    for (int kk = 0; kk < 64; kk += 32) {
      bf16x8 ah[4], al[4], bb[2];
#pragma unroll
      for (int rt = 0; rt < 4; ++rt) {
        ah[rt] = lds_frag(PHI, rt * 16 + rl, kk + kof, 128);
        al[rt] = lds_frag(PLO, rt * 16 + rl, kk + kof, 128);
      }
#pragma unroll
      for (int ct = 0; ct < 2; ++ct) bb[ct] = lds_frag(QS, c0 + ct * 16 + rl, kk + kof, 128);
#pragma unroll
      for (int rt = 0; rt < 4; ++rt)
#pragma unroll
        for (int ct = 0; ct < 2; ++ct) {
          acc[rt][ct] = mfma16(ah[rt], bb[ct], acc[rt][ct]);
          acc[rt][ct] = mfma16(al[rt], bb[ct], acc[rt][ct]);
        }
    }
    __syncthreads();
#pragma unroll
    for (int ct = 0; ct < 2; ++ct)
#pragma unroll
      for (int rt = 0; rt < 4; ++rt)
#pragma unroll
        for (int i = 0; i < 4; ++i)
          lds_put2(XHI, XLO, rt * 16 + ro4 + i, c0 + ct * 16 + rl, 512, acc[rt][ct][i]);
  }
  __syncthreads();

  // x_att = ctx @ Wo^T + Bo (split ctx) -> f32 global
  {
    f32x4 acc[4][2] = {};
    for (int kk = 0; kk < 256; kk += 32) {
      bf16x8 ah[4], al[4], bb[2];
#pragma unroll
      for (int rt = 0; rt < 4; ++rt) {
        ah[rt] = lds_frag(XHI, rt * 16 + rl, kk + kof, 512);
        al[rt] = lds_frag(XLO, rt * 16 + rl, kk + kof, 512);
      }
#pragma unroll
      for (int ct = 0; ct < 2; ++ct)
        bb[ct] = *reinterpret_cast<const bf16x8*>(Wo + (long)(c0 + ct * 16 + rl) * 256 + kk + kof);
#pragma unroll
      for (int rt = 0; rt < 4; ++rt)
#pragma unroll
        for (int ct = 0; ct < 2; ++ct) {
          acc[rt][ct] = mfma16(ah[rt], bb[ct], acc[rt][ct]);
          acc[rt][ct] = mfma16(al[rt], bb[ct], acc[rt][ct]);
        }
    }
#pragma unroll
    for (int ct = 0; ct < 2; ++ct) {
      int c = c0 + ct * 16 + rl;
      float bv = Bo[c];
#pragma unroll
      for (int rt = 0; rt < 4; ++rt)
#pragma unroll
        for (int i = 0; i < 4; ++i)
          Xatt[(R0 + rt * 16 + ro4 + i) * 256 + c] = acc[rt][ct][i] + bv;
    }
  }
}

// ---------------------------------------------------------------------------
// x_ = relu([x | x_att] @ att_w^T + b), split operands, f32 in/out.
// Writes x_ in-place over Xa's rows (staged before write; block-local).
// ---------------------------------------------------------------------------
__global__ __launch_bounds__(256) void gemm_cat(float* __restrict__ Xa,
                                                const float* __restrict__ Xb,
                                                const bf16_t* __restrict__ W,
                                                const float* __restrict__ Bi) {
  __shared__ bf16_t Chi[64 * 512], Clo[64 * 512];  // 64K + 64K
  const int tid = threadIdx.x, lane = tid & 63, wv = tid >> 6;
  const int rl = lane & 15, kof = (lane >> 4) << 3, ro4 = (lane >> 4) << 2;
  const long m0 = (long)blockIdx.x * 64;
  stage_split(Chi, Clo, Xa, m0, 1024, 0, tid, 256);
  stage_split(Chi, Clo, Xb, m0, 1024, 512, tid, 256);
  __syncthreads();
  f32x4 acc[4][4] = {};
  for (int kk = 0; kk < 512; kk += 32) {
    bf16x8 ah[4], al[4], bb[4];
#pragma unroll
    for (int rt = 0; rt < 4; ++rt) {
      ah[rt] = lds_frag(Chi, rt * 16 + rl, kk + kof, 1024);
      al[rt] = lds_frag(Clo, rt * 16 + rl, kk + kof, 1024);
    }
#pragma unroll
    for (int ct = 0; ct < 4; ++ct)
      bb[ct] = *reinterpret_cast<const bf16x8*>(W + (long)(wv * 64 + ct * 16 + rl) * 512 + kk + kof);
#pragma unroll
    for (int rt = 0; rt < 4; ++rt)
#pragma unroll
      for (int ct = 0; ct < 4; ++ct) {
        acc[rt][ct] = mfma16(ah[rt], bb[ct], acc[rt][ct]);
        acc[rt][ct] = mfma16(al[rt], bb[ct], acc[rt][ct]);
      }
  }
#pragma unroll
  for (int ct = 0; ct < 4; ++ct) {
    int c = wv * 64 + ct * 16 + rl;
    float bv = Bi[c];
#pragma unroll
    for (int rt = 0; rt < 4; ++rt)
#pragma unroll
      for (int i = 0; i < 4; ++i)
        Xa[(m0 + rt * 16 + ro4 + i) * 256 + c] = fmaxf(acc[rt][ct][i] + bv, 0.f);
  }
}

// ---------------------------------------------------------------------------
// Fused GRUCell, split operands. Xf = x_ (f32), Hin = h (f32); Hout = h (f32).
// Block = 64 rows, 512 thr / 8 waves, 2 column passes.
// ---------------------------------------------------------------------------
__global__ __launch_bounds__(512) void gru_kernel(const float* __restrict__ Xf,
                                                  const float* __restrict__ Hin,
                                                  const bf16_t* __restrict__ Wih,
                                                  const bf16_t* __restrict__ Whh,
                                                  const float* __restrict__ bih,
                                                  const float* __restrict__ bhh,
                                                  float* __restrict__ Hout) {
  __shared__ bf16_t Xhi[64 * 256], Xlo[64 * 256], Hhi[64 * 256], Hlo[64 * 256];
  const int tid = threadIdx.x, lane = tid & 63, wv = tid >> 6;
  const int rl = lane & 15, kof = (lane >> 4) << 3, ro4 = (lane >> 4) << 2;
  const long m0 = (long)blockIdx.x * 64;
  stage_split(Xhi, Xlo, Xf, m0, 512, 0, tid, 512);
  stage_split(Hhi, Hlo, Hin, m0, 512, 0, tid, 512);
  __syncthreads();
  for (int p = 0; p < 2; ++p) {
    const int c0 = p * 128 + wv * 16;
    f32x4 aI[3][4] = {}, aH[3][4] = {};
    for (int kk = 0; kk < 256; kk += 32) {
      bf16x8 axh[4], axl[4], bI[3];
#pragma unroll
      for (int rt = 0; rt < 4; ++rt) {
        axh[rt] = lds_frag(Xhi, rt * 16 + rl, kk + kof, 512);
        axl[rt] = lds_frag(Xlo, rt * 16 + rl, kk + kof, 512);
      }
#pragma unroll
      for (int g = 0; g < 3; ++g)
        bI[g] = *reinterpret_cast<const bf16x8*>(Wih + (long)(g * 256 + c0 + rl) * 256 + kk + kof);
#pragma unroll
      for (int g = 0; g < 3; ++g)
#pragma unroll
        for (int rt = 0; rt < 4; ++rt) {
          aI[g][rt] = mfma16(axh[rt], bI[g], aI[g][rt]);
          aI[g][rt] = mfma16(axl[rt], bI[g], aI[g][rt]);
        }
    }
    for (int kk = 0; kk < 256; kk += 32) {
      bf16x8 ahh[4], ahl[4], bH[3];
#pragma unroll
      for (int rt = 0; rt < 4; ++rt) {
        ahh[rt] = lds_frag(Hhi, rt * 16 + rl, kk + kof, 512);
        ahl[rt] = lds_frag(Hlo, rt * 16 + rl, kk + kof, 512);
      }
#pragma unroll
      for (int g = 0; g < 3; ++g)
        bH[g] = *reinterpret_cast<const bf16x8*>(Whh + (long)(g * 256 + c0 + rl) * 256 + kk + kof);
#pragma unroll
      for (int g = 0; g < 3; ++g)
#pragma unroll
        for (int rt = 0; rt < 4; ++rt) {
          aH[g][rt] = mfma16(ahh[rt], bH[g], aH[g][rt]);
          aH[g][rt] = mfma16(ahl[rt], bH[g], aH[g][rt]);
        }
    }
    const int c = c0 + rl;
    float bir = bih[c],        bhr = bhh[c];
    float biz = bih[256 + c],  bhz = bhh[256 + c];
    float bin_ = bih[512 + c], bhn = bhh[512 + c];
#pragma unroll
    for (int rt = 0; rt < 4; ++rt)
#pragma unroll
      for (int i = 0; i < 4; ++i) {
        int rloc = rt * 16 + ro4 + i;
        float rg = 1.f / (1.f + __expf(-(aI[0][rt][i] + bir + aH[0][rt][i] + bhr)));
        float zg = 1.f / (1.f + __expf(-(aI[1][rt][i] + biz + aH[1][rt][i] + bhz)));
        float nx = aI[2][rt][i] + bin_ + rg * (aH[2][rt][i] + bhn);
        float ng = 1.f - 2.f / (__expf(2.f * nx) + 1.f);  // tanh, saturation-safe
        float hv = Hin[(m0 + rloc) * 256 + c];
        Hout[(m0 + rloc) * 256 + c] = (1.f - zg) * ng + zg * hv;
      }
  }
}

// tactic_q = h @ fc2_w^T + b, split h. 256 thr / 4 waves, 16 rows per wave.
__global__ __launch_bounds__(256) void fc2_kernel(const float* __restrict__ h,
                                                  const bf16_t* __restrict__ Wt,
                                                  const float* __restrict__ bt,
                                                  float* __restrict__ out) {
  __shared__ bf16_t Hhi[64 * 256], Hlo[64 * 256];
  const int tid = threadIdx.x, lane = tid & 63, wv = tid >> 6;
  const int rl = lane & 15, kof = (lane >> 4) << 3, ro4 = (lane >> 4) << 2;
  const long m0 = (long)blockIdx.x * 64;
  stage_split(Hhi, Hlo, h, m0, 512, 0, tid, 256);
  __syncthreads();
  f32x4 acc = {};
  for (int kk = 0; kk < 256; kk += 32) {
    bf16x8 ah = lds_frag(Hhi, wv * 16 + rl, kk + kof, 512);
    bf16x8 al = lds_frag(Hlo, wv * 16 + rl, kk + kof, 512);
    bf16x8 bb = *reinterpret_cast<const bf16x8*>(Wt + (long)rl * 256 + kk + kof);
    acc = mfma16(ah, bb, acc);
    acc = mfma16(al, bb, acc);
  }
  float bv = bt[rl];
#pragma unroll
  for (int i = 0; i < 4; ++i) out[(m0 + wv * 16 + ro4 + i) * 16 + rl] = acc[i] + bv;
}

// int32 bool -> f32 {0,1} copy, 4 elems/thread
__global__ __launch_bounds__(256) void drop_copy(const int* __restrict__ d,
                                                 float* __restrict__ o) {
  long i = (long)blockIdx.x * 256 + threadIdx.x;
  int4 v = reinterpret_cast<const int4*>(d)[i];
  float4 r;
  r.x = v.x ? 1.f : 0.f;
  r.y = v.y ? 1.f : 0.f;
  r.z = v.z ? 1.f : 0.f;
  r.w = v.w ? 1.f : 0.f;
  reinterpret_cast<float4*>(o)[i] = r;
}

extern "C" void kernel_launch(void* const* d_in, const int* in_sizes, int n_in,
                              void* d_out, int out_size, void* d_ws, size_t ws_size,
                              hipStream_t stream) {
  (void)in_sizes; (void)n_in; (void)out_size; (void)ws_size;
  const float* inputs      = (const float*)d_in[0];
  const float* hidden      = (const float*)d_in[1];
  const int*   drp         = (const int*)d_in[2];   // bool pushed as int32
  // d_in[3] = t (unused)
  const float* fc_gru_w    = (const float*)d_in[4];
  const float* fc_gru_b    = (const float*)d_in[5];
  const float* in_proj_w   = (const float*)d_in[6];
  const float* in_proj_b   = (const float*)d_in[7];
  const float* out_proj_w  = (const float*)d_in[8];
  const float* out_proj_b  = (const float*)d_in[9];
  const float* att_w       = (const float*)d_in[10];
  const float* att_b       = (const float*)d_in[11];
  const float* gru_wih     = (const float*)d_in[12];
  const float* gru_whh     = (const float*)d_in[13];
  const float* gru_bih     = (const float*)d_in[14];
  const float* gru_bhh     = (const float*)d_in[15];
  const float* fc2_w       = (const float*)d_in[16];
  const float* fc2_b       = (const float*)d_in[17];

  float* out_t = (float*)d_out;          // [M,16]
  float* out_h = out_t + MTOT * 16;      // [M,256] f32: x_att, then h
  float* out_d = out_h + MTOT * 256;     // [B*64*64] f32

  float*  A  = (float*)d_ws;             // [M,256] f32: x, then x_   (128 MB)
  bf16_t* Wb = (bf16_t*)(A + MTOT * 256);  // bf16 weights (1.7 MB)

  // 0) weights f32 -> bf16
  cvt_weights<<<836, 256, 0, stream>>>(fc_gru_w, in_proj_w, out_proj_w, att_w,
                                       gru_wih, gru_whh, fc2_w, Wb);
  // 1) x = relu(inputs @ fc_gru_w^T + b) -> A (f32)
  gemm1<<<2048, 256, 0, stream>>>(inputs, Wb, fc_gru_b, A);
  // 2) fused attention: x -> x_att (f32, parked in out_h)
  attn_kernel<<<2048, 512, 0, stream>>>(A, out_h, Wb + 65536, in_proj_b,
                                        Wb + 262144, out_proj_b, drp);
  // 3) x_ = relu([x | x_att] @ att_w^T + b) -> A (f32, in-place)
  gemm_cat<<<2048, 256, 0, stream>>>(A, out_h, Wb + 327680, att_b);
  // 4) GRU: x_ (A) + hidden -> h -> out_h (f32, overwrites x_att)
  gru_kernel<<<2048, 512, 0, stream>>>(A, hidden, Wb + 458752, Wb + 655360,
                                       gru_bih, gru_bhh, out_h);
  // 5) tactic_q = h @ fc2_w^T + b -> out_t
  fc2_kernel<<<2048, 256, 0, stream>>>(out_h, Wb + 851968, fc2_b, out_t);
  // 6) drop mask echo as f32 (8388608 elems / 4 per thread / 256 = 8192 blocks)
  drop_copy<<<8192, 256, 0, stream>>>(drp, out_d);
}

// Round 6
// 1430.868 us; speedup vs baseline: 1.6027x; 1.6027x over previous
//
#include <hip/hip_runtime.h>

typedef __bf16 bf16_t;
using bf16x8 = __bf16 __attribute__((ext_vector_type(8)));
using f32x4  = float __attribute__((ext_vector_type(4)));

// B=2048, N=64, D=256, H=256, T=16
static constexpr long MTOT = 131072;   // B*N

__device__ __forceinline__ f32x4 mfma16(bf16x8 a, bf16x8 b, f32x4 c) {
  return __builtin_amdgcn_mfma_f32_16x16x32_bf16(a, b, c, 0, 0, 0);
}

// Swizzled LDS tiles: element (row,k) at byte row*rowBytes + ((k*2 + colOff) ^ ((row&7)<<4)).
__device__ __forceinline__ bf16x8 lds_frag(const bf16_t* base, int row, int k, int rowBytes) {
  int byte = row * rowBytes + ((k << 1) ^ ((row & 7) << 4));
  return *reinterpret_cast<const bf16x8*>(reinterpret_cast<const char*>(base) + byte);
}
__device__ __forceinline__ void lds_put(bf16_t* base, int row, int col, int rowBytes, float v) {
  int byte = row * rowBytes + ((col << 1) ^ ((row & 7) << 4));
  *reinterpret_cast<bf16_t*>(reinterpret_cast<char*>(base) + byte) = (bf16_t)v;
}
__device__ __forceinline__ void lds_put2(bf16_t* hi, bf16_t* lo, int row, int col,
                                         int rowBytes, float v) {
  int byte = row * rowBytes + ((col << 1) ^ ((row & 7) << 4));
  bf16_t h = (bf16_t)v;
  bf16_t l = (bf16_t)(v - (float)h);
  *reinterpret_cast<bf16_t*>(reinterpret_cast<char*>(hi) + byte) = h;
  *reinterpret_cast<bf16_t*>(reinterpret_cast<char*>(lo) + byte) = l;
}

// Stage a [64 x 256] f32 tile (lda=256) -> split hi/lo bf16 swizzled LDS tiles.
__device__ __forceinline__ void stage_split(bf16_t* hi, bf16_t* lo, const float* src,
                                            long row0, int rowBytesLds, int colOffBytes,
                                            int tid, int nthr) {
  for (int e = tid * 4; e < 64 * 256; e += nthr * 4) {
    int r = e >> 8, c = e & 255;
    float4 v = *reinterpret_cast<const float4*>(src + (row0 + r) * 256 + c);
    bf16_t h4[4], l4[4];
    h4[0] = (bf16_t)v.x; l4[0] = (bf16_t)(v.x - (float)h4[0]);
    h4[1] = (bf16_t)v.y; l4[1] = (bf16_t)(v.y - (float)h4[1]);
    h4[2] = (bf16_t)v.z; l4[2] = (bf16_t)(v.z - (float)h4[2]);
    h4[3] = (bf16_t)v.w; l4[3] = (bf16_t)(v.w - (float)h4[3]);
    int db = r * rowBytesLds + (((c << 1) + colOffBytes) ^ ((r & 7) << 4));
    *reinterpret_cast<uint2*>(reinterpret_cast<char*>(hi) + db) = *reinterpret_cast<const uint2*>(h4);
    *reinterpret_cast<uint2*>(reinterpret_cast<char*>(lo) + db) = *reinterpret_cast<const uint2*>(l4);
  }
}

// ---------------------------------------------------------------------------
// Weights f32 -> bf16 in ws. Offsets (elements): fc_gru_w 0, in_proj_w 65536,
// out_proj_w 262144, att_w 327680, gru_wih 458752, gru_whh 655360, fc2_w 851968.
// ---------------------------------------------------------------------------
__global__ __launch_bounds__(256) void cvt_weights(const float* __restrict__ w0,
                                                   const float* __restrict__ w1,
                                                   const float* __restrict__ w2,
                                                   const float* __restrict__ w3,
                                                   const float* __restrict__ w4,
                                                   const float* __restrict__ w5,
                                                   const float* __restrict__ w6,
                                                   bf16_t* __restrict__ dst) {
  long e = ((long)blockIdx.x * 256 + threadIdx.x) * 4;
  const float* src; long off;
  if (e < 65536)       { src = w0; off = 0; }
  else if (e < 262144) { src = w1; off = 65536; }
  else if (e < 327680) { src = w2; off = 262144; }
  else if (e < 458752) { src = w3; off = 327680; }
  else if (e < 655360) { src = w4; off = 458752; }
  else if (e < 851968) { src = w5; off = 655360; }
  else                 { src = w6; off = 851968; }
  float4 v = *reinterpret_cast<const float4*>(src + (e - off));
  bf16_t o[4] = {(bf16_t)v.x, (bf16_t)v.y, (bf16_t)v.z, (bf16_t)v.w};
  *reinterpret_cast<uint2*>(dst + e) = *reinterpret_cast<const uint2*>(o);
}

// ---------------------------------------------------------------------------
// x = relu(inputs @ fc_gru_w^T + b): f32 in (split), f32 out. Tile 64x256.
// ---------------------------------------------------------------------------
__global__ __launch_bounds__(256, 2) void gemm1(const float* __restrict__ X,
                                                const bf16_t* __restrict__ W,
                                                const float* __restrict__ Bi,
                                                float* __restrict__ C) {
  __shared__ bf16_t Ihi[64 * 256], Ilo[64 * 256];
  const int tid = threadIdx.x, lane = tid & 63, wv = tid >> 6;
  const int rl = lane & 15, kof = (lane >> 4) << 3, ro4 = (lane >> 4) << 2;
  const long m0 = (long)blockIdx.x * 64;
  stage_split(Ihi, Ilo, X, m0, 512, 0, tid, 256);
  __syncthreads();
  f32x4 acc[4][4] = {};
  for (int kk = 0; kk < 256; kk += 32) {
    bf16x8 ah[4], al[4], bb[4];
#pragma unroll
    for (int rt = 0; rt < 4; ++rt) {
      ah[rt] = lds_frag(Ihi, rt * 16 + rl, kk + kof, 512);
      al[rt] = lds_frag(Ilo, rt * 16 + rl, kk + kof, 512);
    }
#pragma unroll
    for (int ct = 0; ct < 4; ++ct)
      bb[ct] = *reinterpret_cast<const bf16x8*>(W + (long)(wv * 64 + ct * 16 + rl) * 256 + kk + kof);
#pragma unroll
    for (int rt = 0; rt < 4; ++rt)
#pragma unroll
      for (int ct = 0; ct < 4; ++ct) {
        acc[rt][ct] = mfma16(ah[rt], bb[ct], acc[rt][ct]);
        acc[rt][ct] = mfma16(al[rt], bb[ct], acc[rt][ct]);
      }
  }
#pragma unroll
  for (int ct = 0; ct < 4; ++ct) {
    int c = wv * 64 + ct * 16 + rl;
    float bv = Bi[c];
#pragma unroll
    for (int rt = 0; rt < 4; ++rt)
#pragma unroll
      for (int i = 0; i < 4; ++i)
        C[(m0 + rt * 16 + ro4 + i) * 256 + c] = fmaxf(acc[rt][ct][i] + bv, 0.f);
  }
}

// ---------------------------------------------------------------------------
// Fused per-sample attention, split-precision. Block = 1 sample, 512 thr/8 waves.
// Reads x (f32 [M,256]), writes x_att (f32 [M,256]). Mask is INT32 (bool->int).
// ---------------------------------------------------------------------------
__global__ __launch_bounds__(512, 2) void attn_kernel(const float* __restrict__ Xf,
                                                      float* __restrict__ Xatt,
                                                      const bf16_t* __restrict__ Wqkv,
                                                      const float* __restrict__ Bqkv,
                                                      const bf16_t* __restrict__ Wo,
                                                      const float* __restrict__ Bo,
                                                      const int* __restrict__ drop) {
  __shared__ __align__(16) char buf[147456];
  bf16_t* XHI = reinterpret_cast<bf16_t*>(buf);            // 32K, swz rowBytes 512
  bf16_t* XLO = reinterpret_cast<bf16_t*>(buf + 32768);    // 32K
  bf16_t* QS  = reinterpret_cast<bf16_t*>(buf + 65536);    // 32K, swz 512; later V^T swz 128
  bf16_t* KS  = reinterpret_cast<bf16_t*>(buf + 98304);    // 32K, swz 512; later PHI/PLO swz 128
  bf16_t* PHI = KS;                                        // 8K  [64][64]
  bf16_t* PLO = reinterpret_cast<bf16_t*>(buf + 98304 + 8192);
  float*  SS  = reinterpret_cast<float*>(buf + 131072);    // 16K [64][64]
  const int tid = threadIdx.x, lane = tid & 63, wv = tid >> 6;
  const int rl = lane & 15, kof = (lane >> 4) << 3, ro4 = (lane >> 4) << 2;
  const int b = blockIdx.x;
  const long R0 = (long)b * 64;
  stage_split(XHI, XLO, Xf, R0, 512, 0, tid, 512);
  __syncthreads();
  const int c0 = wv * 32;

  // q and k GEMMs (split x) -> bf16 swizzled LDS
  for (int which = 0; which < 2; ++which) {
    const bf16_t* Wp = Wqkv + (long)which * 65536;
    bf16_t* outp = which ? KS : QS;
    f32x4 acc[4][2] = {};
    for (int kk = 0; kk < 256; kk += 32) {
      bf16x8 ah[4], al[4], bb[2];
#pragma unroll
      for (int rt = 0; rt < 4; ++rt) {
        ah[rt] = lds_frag(XHI, rt * 16 + rl, kk + kof, 512);
        al[rt] = lds_frag(XLO, rt * 16 + rl, kk + kof, 512);
      }
#pragma unroll
      for (int ct = 0; ct < 2; ++ct)
        bb[ct] = *reinterpret_cast<const bf16x8*>(Wp + (long)(c0 + ct * 16 + rl) * 256 + kk + kof);
#pragma unroll
      for (int rt = 0; rt < 4; ++rt)
#pragma unroll
        for (int ct = 0; ct < 2; ++ct) {
          acc[rt][ct] = mfma16(ah[rt], bb[ct], acc[rt][ct]);
          acc[rt][ct] = mfma16(al[rt], bb[ct], acc[rt][ct]);
        }
    }
#pragma unroll
    for (int ct = 0; ct < 2; ++ct) {
      int c = c0 + ct * 16 + rl;
      float bv = Bqkv[which * 256 + c];
#pragma unroll
      for (int rt = 0; rt < 4; ++rt)
#pragma unroll
        for (int i = 0; i < 4; ++i) lds_put(outp, rt * 16 + ro4 + i, c, 512, acc[rt][ct][i] + bv);
    }
  }
  __syncthreads();

  // scores = q k^T * scale, masked (int32 mask) -> SS f32
  {
    const int rt0 = (wv & 3) * 16, sc0 = (wv >> 2) * 32;
    f32x4 acc[2] = {};
    for (int kk = 0; kk < 256; kk += 32) {
      bf16x8 a = lds_frag(QS, rt0 + rl, kk + kof, 512);
#pragma unroll
      for (int ct = 0; ct < 2; ++ct) {
        bf16x8 bb = lds_frag(KS, sc0 + ct * 16 + rl, kk + kof, 512);
        acc[ct] = mfma16(a, bb, acc[ct]);
      }
    }
#pragma unroll
    for (int ct = 0; ct < 2; ++ct)
#pragma unroll
      for (int i = 0; i < 4; ++i) {
        int rr = rt0 + ro4 + i, cc = sc0 + ct * 16 + rl;
        float s = acc[ct][i] * 0.0625f;
        if (drop[(long)b * 4096 + rr * 64 + cc]) s = -1e9f;
        SS[rr * 64 + cc] = s;
      }
  }
  __syncthreads();

  // v GEMM (split x) -> V^T [256][64] bf16 over Q region (q dead)
  {
    const bf16_t* Wp = Wqkv + (long)2 * 65536;
    f32x4 acc[4][2] = {};
    for (int kk = 0; kk < 256; kk += 32) {
      bf16x8 ah[4], al[4], bb[2];
#pragma unroll
      for (int rt = 0; rt < 4; ++rt) {
        ah[rt] = lds_frag(XHI, rt * 16 + rl, kk + kof, 512);
        al[rt] = lds_frag(XLO, rt * 16 + rl, kk + kof, 512);
      }
#pragma unroll
      for (int ct = 0; ct < 2; ++ct)
        bb[ct] = *reinterpret_cast<const bf16x8*>(Wp + (long)(c0 + ct * 16 + rl) * 256 + kk + kof);
#pragma unroll
      for (int rt = 0; rt < 4; ++rt)
#pragma unroll
        for (int ct = 0; ct < 2; ++ct) {
          acc[rt][ct] = mfma16(ah[rt], bb[ct], acc[rt][ct]);
          acc[rt][ct] = mfma16(al[rt], bb[ct], acc[rt][ct]);
        }
    }
#pragma unroll
    for (int ct = 0; ct < 2; ++ct) {
      int c = c0 + ct * 16 + rl;
      float bv = Bqkv[512 + c];
#pragma unroll
      for (int rt = 0; rt < 4; ++rt)
#pragma unroll
        for (int i = 0; i < 4; ++i) {
          int j = rt * 16 + ro4 + i;                    // agent (key) index
          lds_put(QS, c, j, 128, acc[rt][ct][i] + bv);  // V^T[c][j]
        }
    }
  }
  // wave-parallel softmax -> split P over K region (k dead)
  for (int j = 0; j < 8; ++j) {
    int rr = wv * 8 + j;
    float s = SS[rr * 64 + lane];
    float m = s;
#pragma unroll
    for (int off = 32; off >= 1; off >>= 1) m = fmaxf(m, __shfl_xor(m, off));
    float e = __expf(s - m);
    float sum = e;
#pragma unroll
    for (int off = 32; off >= 1; off >>= 1) sum += __shfl_xor(sum, off);
    lds_put2(PHI, PLO, rr, lane, 128, e / sum);
  }
  __syncthreads();

  // ctx = P @ V (split P) -> split ctx over X region (x dead)
  {
    f32x4 acc[4][2] = {};
    for (int kk = 0; kk < 64; kk += 32) {
      bf16x8 ah[4], al[4], bb[2];
#pragma unroll
      for (int rt = 0; rt < 4; ++rt) {
        ah[rt] = lds_frag(PHI, rt * 16 + rl, kk + kof, 128);
        al[rt] = lds_frag(PLO, rt * 16 + rl, kk + kof, 128);
      }
#pragma unroll
      for (int ct = 0; ct < 2; ++ct) bb[ct] = lds_frag(QS, c0 + ct * 16 + rl, kk + kof, 128);
#pragma unroll
      for (int rt = 0; rt < 4; ++rt)
#pragma unroll
        for (int ct = 0; ct < 2; ++ct) {
          acc[rt][ct] = mfma16(ah[rt], bb[ct], acc[rt][ct]);
          acc[rt][ct] = mfma16(al[rt], bb[ct], acc[rt][ct]);
        }
    }
    __syncthreads();
#pragma unroll
    for (int ct = 0; ct < 2; ++ct)
#pragma unroll
      for (int rt = 0; rt < 4; ++rt)
#pragma unroll
        for (int i = 0; i < 4; ++i)
          lds_put2(XHI, XLO, rt * 16 + ro4 + i, c0 + ct * 16 + rl, 512, acc[rt][ct][i]);
  }
  __syncthreads();

  // x_att = ctx @ Wo^T + Bo (split ctx) -> f32 global
  {
    f32x4 acc[4][2] = {};
    for (int kk = 0; kk < 256; kk += 32) {
      bf16x8 ah[4], al[4], bb[2];
#pragma unroll
      for (int rt = 0; rt < 4; ++rt) {
        ah[rt] = lds_frag(XHI, rt * 16 + rl, kk + kof, 512);
        al[rt] = lds_frag(XLO, rt * 16 + rl, kk + kof, 512);
      }
#pragma unroll
      for (int ct = 0; ct < 2; ++ct)
        bb[ct] = *reinterpret_cast<const bf16x8*>(Wo + (long)(c0 + ct * 16 + rl) * 256 + kk + kof);
#pragma unroll
      for (int rt = 0; rt < 4; ++rt)
#pragma unroll
        for (int ct = 0; ct < 2; ++ct) {
          acc[rt][ct] = mfma16(ah[rt], bb[ct], acc[rt][ct]);
          acc[rt][ct] = mfma16(al[rt], bb[ct], acc[rt][ct]);
        }
    }
#pragma unroll
    for (int ct = 0; ct < 2; ++ct) {
      int c = c0 + ct * 16 + rl;
      float bv = Bo[c];
#pragma unroll
      for (int rt = 0; rt < 4; ++rt)
#pragma unroll
        for (int i = 0; i < 4; ++i)
          Xatt[(R0 + rt * 16 + ro4 + i) * 256 + c] = acc[rt][ct][i] + bv;
    }
  }
}

// ---------------------------------------------------------------------------
// x_ = relu([x | x_att] @ att_w^T + b), split operands, f32 in/out.
// ---------------------------------------------------------------------------
__global__ __launch_bounds__(256, 2) void gemm_cat(float* __restrict__ Xa,
                                                   const float* __restrict__ Xb,
                                                   const bf16_t* __restrict__ W,
                                                   const float* __restrict__ Bi) {
  __shared__ bf16_t Chi[64 * 512], Clo[64 * 512];  // 64K + 64K
  const int tid = threadIdx.x, lane = tid & 63, wv = tid >> 6;
  const int rl = lane & 15, kof = (lane >> 4) << 3, ro4 = (lane >> 4) << 2;
  const long m0 = (long)blockIdx.x * 64;
  stage_split(Chi, Clo, Xa, m0, 1024, 0, tid, 256);
  stage_split(Chi, Clo, Xb, m0, 1024, 512, tid, 256);
  __syncthreads();
  f32x4 acc[4][4] = {};
  for (int kk = 0; kk < 512; kk += 32) {
    bf16x8 ah[4], al[4], bb[4];
#pragma unroll
    for (int rt = 0; rt < 4; ++rt) {
      ah[rt] = lds_frag(Chi, rt * 16 + rl, kk + kof, 1024);
      al[rt] = lds_frag(Clo, rt * 16 + rl, kk + kof, 1024);
    }
#pragma unroll
    for (int ct = 0; ct < 4; ++ct)
      bb[ct] = *reinterpret_cast<const bf16x8*>(W + (long)(wv * 64 + ct * 16 + rl) * 512 + kk + kof);
#pragma unroll
    for (int rt = 0; rt < 4; ++rt)
#pragma unroll
      for (int ct = 0; ct < 4; ++ct) {
        acc[rt][ct] = mfma16(ah[rt], bb[ct], acc[rt][ct]);
        acc[rt][ct] = mfma16(al[rt], bb[ct], acc[rt][ct]);
      }
  }
#pragma unroll
  for (int ct = 0; ct < 4; ++ct) {
    int c = wv * 64 + ct * 16 + rl;
    float bv = Bi[c];
#pragma unroll
    for (int rt = 0; rt < 4; ++rt)
#pragma unroll
      for (int i = 0; i < 4; ++i)
        Xa[(m0 + rt * 16 + ro4 + i) * 256 + c] = fmaxf(acc[rt][ct][i] + bv, 0.f);
  }
}

// ---------------------------------------------------------------------------
// Fused GRUCell, split operands. 2 M-tiles per block (weight reuse), 512 thr.
// __launch_bounds__(512,2): LDS already limits to 1 block/CU (2 waves/SIMD);
// allow 256 VGPRs so the 96-VGPR accumulator set doesn't spill to scratch.
// ---------------------------------------------------------------------------
__global__ __launch_bounds__(512, 2) void gru_kernel(const float* __restrict__ Xf,
                                                     const float* __restrict__ Hin,
                                                     const bf16_t* __restrict__ Wih,
                                                     const bf16_t* __restrict__ Whh,
                                                     const float* __restrict__ bih,
                                                     const float* __restrict__ bhh,
                                                     float* __restrict__ Hout) {
  __shared__ bf16_t Xhi[64 * 256], Xlo[64 * 256], Hhi[64 * 256], Hlo[64 * 256];
  const int tid = threadIdx.x, lane = tid & 63, wv = tid >> 6;
  const int rl = lane & 15, kof = (lane >> 4) << 3, ro4 = (lane >> 4) << 2;
  for (int t = 0; t < 2; ++t) {
    const long m0 = ((long)blockIdx.x * 2 + t) * 64;
    if (t) __syncthreads();  // all waves done reading LDS before re-stage
    stage_split(Xhi, Xlo, Xf, m0, 512, 0, tid, 512);
    stage_split(Hhi, Hlo, Hin, m0, 512, 0, tid, 512);
    __syncthreads();
    for (int p = 0; p < 2; ++p) {
      const int c0 = p * 128 + wv * 16;
      f32x4 aI[3][4] = {}, aH[3][4] = {};
      for (int kk = 0; kk < 256; kk += 32) {
        bf16x8 axh[4], axl[4], bI[3];
#pragma unroll
        for (int rt = 0; rt < 4; ++rt) {
          axh[rt] = lds_frag(Xhi, rt * 16 + rl, kk + kof, 512);
          axl[rt] = lds_frag(Xlo, rt * 16 + rl, kk + kof, 512);
        }
#pragma unroll
        for (int g = 0; g < 3; ++g)
          bI[g] = *reinterpret_cast<const bf16x8*>(Wih + (long)(g * 256 + c0 + rl) * 256 + kk + kof);
#pragma unroll
        for (int g = 0; g < 3; ++g)
#pragma unroll
          for (int rt = 0; rt < 4; ++rt) {
            aI[g][rt] = mfma16(axh[rt], bI[g], aI[g][rt]);
            aI[g][rt] = mfma16(axl[rt], bI[g], aI[g][rt]);
          }
      }
      for (int kk = 0; kk < 256; kk += 32) {
        bf16x8 ahh[4], ahl[4], bH[3];
#pragma unroll
        for (int rt = 0; rt < 4; ++rt) {
          ahh[rt] = lds_frag(Hhi, rt * 16 + rl, kk + kof, 512);
          ahl[rt] = lds_frag(Hlo, rt * 16 + rl, kk + kof, 512);
        }
#pragma unroll
        for (int g = 0; g < 3; ++g)
          bH[g] = *reinterpret_cast<const bf16x8*>(Whh + (long)(g * 256 + c0 + rl) * 256 + kk + kof);
#pragma unroll
        for (int g = 0; g < 3; ++g)
#pragma unroll
          for (int rt = 0; rt < 4; ++rt) {
            aH[g][rt] = mfma16(ahh[rt], bH[g], aH[g][rt]);
            aH[g][rt] = mfma16(ahl[rt], bH[g], aH[g][rt]);
          }
      }
      const int c = c0 + rl;
      float bir = bih[c],        bhr = bhh[c];
      float biz = bih[256 + c],  bhz = bhh[256 + c];
      float bin_ = bih[512 + c], bhn = bhh[512 + c];
#pragma unroll
      for (int rt = 0; rt < 4; ++rt)
#pragma unroll
        for (int i = 0; i < 4; ++i) {
          int rloc = rt * 16 + ro4 + i;
          float rg = 1.f / (1.f + __expf(-(aI[0][rt][i] + bir + aH[0][rt][i] + bhr)));
          float zg = 1.f / (1.f + __expf(-(aI[1][rt][i] + biz + aH[1][rt][i] + bhz)));
          float nx = aI[2][rt][i] + bin_ + rg * (aH[2][rt][i] + bhn);
          float ng = 1.f - 2.f / (__expf(2.f * nx) + 1.f);  // tanh, saturation-safe
          float hv = Hin[(m0 + rloc) * 256 + c];
          Hout[(m0 + rloc) * 256 + c] = (1.f - zg) * ng + zg * hv;
        }
    }
  }
}

// tactic_q = h @ fc2_w^T + b, split h. 256 thr / 4 waves, 16 rows per wave.
__global__ __launch_bounds__(256, 2) void fc2_kernel(const float* __restrict__ h,
                                                     const bf16_t* __restrict__ Wt,
                                                     const float* __restrict__ bt,
                                                     float* __restrict__ out) {
  __shared__ bf16_t Hhi[64 * 256], Hlo[64 * 256];
  const int tid = threadIdx.x, lane = tid & 63, wv = tid >> 6;
  const int rl = lane & 15, kof = (lane >> 4) << 3, ro4 = (lane >> 4) << 2;
  const long m0 = (long)blockIdx.x * 64;
  stage_split(Hhi, Hlo, h, m0, 512, 0, tid, 256);
  __syncthreads();
  f32x4 acc = {};
  for (int kk = 0; kk < 256; kk += 32) {
    bf16x8 ah = lds_frag(Hhi, wv * 16 + rl, kk + kof, 512);
    bf16x8 al = lds_frag(Hlo, wv * 16 + rl, kk + kof, 512);
    bf16x8 bb = *reinterpret_cast<const bf16x8*>(Wt + (long)rl * 256 + kk + kof);
    acc = mfma16(ah, bb, acc);
    acc = mfma16(al, bb, acc);
  }
  float bv = bt[rl];
#pragma unroll
  for (int i = 0; i < 4; ++i) out[(m0 + wv * 16 + ro4 + i) * 16 + rl] = acc[i] + bv;
}

// int32 bool -> f32 {0,1} copy, 4 elems/thread
__global__ __launch_bounds__(256) void drop_copy(const int* __restrict__ d,
                                                 float* __restrict__ o) {
  long i = (long)blockIdx.x * 256 + threadIdx.x;
  int4 v = reinterpret_cast<const int4*>(d)[i];
  float4 r;
  r.x = v.x ? 1.f : 0.f;
  r.y = v.y ? 1.f : 0.f;
  r.z = v.z ? 1.f : 0.f;
  r.w = v.w ? 1.f : 0.f;
  reinterpret_cast<float4*>(o)[i] = r;
}

extern "C" void kernel_launch(void* const* d_in, const int* in_sizes, int n_in,
                              void* d_out, int out_size, void* d_ws, size_t ws_size,
                              hipStream_t stream) {
  (void)in_sizes; (void)n_in; (void)out_size; (void)ws_size;
  const float* inputs      = (const float*)d_in[0];
  const float* hidden      = (const float*)d_in[1];
  const int*   drp         = (const int*)d_in[2];   // bool pushed as int32
  // d_in[3] = t (unused)
  const float* fc_gru_w    = (const float*)d_in[4];
  const float* fc_gru_b    = (const float*)d_in[5];
  const float* in_proj_w   = (const float*)d_in[6];
  const float* in_proj_b   = (const float*)d_in[7];
  const float* out_proj_w  = (const float*)d_in[8];
  const float* out_proj_b  = (const float*)d_in[9];
  const float* att_w       = (const float*)d_in[10];
  const float* att_b       = (const float*)d_in[11];
  const float* gru_wih     = (const float*)d_in[12];
  const float* gru_whh     = (const float*)d_in[13];
  const float* gru_bih     = (const float*)d_in[14];
  const float* gru_bhh     = (const float*)d_in[15];
  const float* fc2_w       = (const float*)d_in[16];
  const float* fc2_b       = (const float*)d_in[17];

  float* out_t = (float*)d_out;          // [M,16]
  float* out_h = out_t + MTOT * 16;      // [M,256] f32: x_att, then h
  float* out_d = out_h + MTOT * 256;     // [B*64*64] f32

  float*  A  = (float*)d_ws;             // [M,256] f32: x, then x_   (128 MB)
  bf16_t* Wb = (bf16_t*)(A + MTOT * 256);  // bf16 weights (1.7 MB)

  // 0) weights f32 -> bf16
  cvt_weights<<<836, 256, 0, stream>>>(fc_gru_w, in_proj_w, out_proj_w, att_w,
                                       gru_wih, gru_whh, fc2_w, Wb);
  // 1) x = relu(inputs @ fc_gru_w^T + b) -> A (f32)
  gemm1<<<2048, 256, 0, stream>>>(inputs, Wb, fc_gru_b, A);
  // 2) fused attention: x -> x_att (f32, parked in out_h)
  attn_kernel<<<2048, 512, 0, stream>>>(A, out_h, Wb + 65536, in_proj_b,
                                        Wb + 262144, out_proj_b, drp);
  // 3) x_ = relu([x | x_att] @ att_w^T + b) -> A (f32, in-place)
  gemm_cat<<<2048, 256, 0, stream>>>(A, out_h, Wb + 327680, att_b);
  // 4) GRU: x_ (A) + hidden -> h -> out_h (f32, overwrites x_att); 2 tiles/block
  gru_kernel<<<1024, 512, 0, stream>>>(A, hidden, Wb + 458752, Wb + 655360,
                                       gru_bih, gru_bhh, out_h);
  // 5) tactic_q = h @ fc2_w^T + b -> out_t
  fc2_kernel<<<2048, 256, 0, stream>>>(out_h, Wb + 851968, fc2_b, out_t);
  // 6) drop mask echo as f32 (8388608 elems / 4 per thread / 256 = 8192 blocks)
  drop_copy<<<8192, 256, 0, stream>>>(drp, out_d);
}